// Round 13
// baseline (37.376 us; speedup 1.0000x reference)
//
#include <hip/hip_runtime.h>

// SASA local self-attention, fully fused, f32 I/O.
// B=4, C=64, H=W=96, g=8, og=ig=8, k=7, pad=3.
// Block = (b, group, channel-quarter) x 32x16 tile; 2 output channels/block.
// 256 threads, each owns 2 vertically-adjacent pixels.
// R13: R5 base (best, 28.6us) with the two oc passes FUSED into one unrolled
// row walk: 14 ds_read_b64 per row then 56 taps across 4 independent streams,
// no serialization between rows -> compiler can hoist row i+1 reads above
// row i compute (the R10 ablation showed reads = 17us of the plateau).
// k,v float2 in LDS, row stride 25 (free 2-way bank alias).
// exp2-prescaled softmax, no max-subtraction (|logit|*log2e << 127).
// XCD-aware bijective block swizzle (2304 % 8 == 0).

constexpr int Bc = 4, Cc = 64, Hc = 96, Wc = 96;
constexpr int G = 8, OG = 8, IG = 8, KK = 7, PAD = 3;
constexpr int TH = 32, TW = 16;
constexpr int SH = TH + KK - 1;    // 38 halo rows
constexpr int SWD = TW + KK - 1;   // 22 halo cols (data)
constexpr int SW2 = 25;            // LDS row stride in float2 units
constexpr int TILES_H = Hc / TH, TILES_W = Wc / TW;  // 3 x 6
constexpr int TILES = TILES_H * TILES_W;             // 18
constexpr int PLANE = Hc * Wc;
constexpr int OCB = 2;             // output channels per block (4 quarters)
constexpr int NB = Bc * G * 4 * TILES;               // 2304
constexpr float LOG2E = 1.4426950408889634f;

// Fused-oc tap walk. HALFC literal: 0 -> emb varies with patch row i, 1 -> col j.
// Streams: (oc0,px0)(oc1,px0)(oc0,px1)(oc1,px1); px0 rows i=0..6, px1 i=1..7.
#define PHASE2(HALFC)                                                             \
  {                                                                               \
    float s00 = 0.f, s10 = 0.f, o00 = 0.f, o10 = 0.f;  /* px0: oc0, oc1 */        \
    float s01 = 0.f, s11 = 0.f, o01 = 0.f, o11 = 0.f;  /* px1 */                  \
    const float2* rp0 = &kvs[0][r0][tx];                                          \
    const float2* rp1 = &kvs[1][r0][tx];                                          \
    _Pragma("unroll")                                                             \
    for (int i = 0; i < 8; ++i) {                                                 \
      float2 row0[KK], row1[KK];                                                  \
      _Pragma("unroll")                                                           \
      for (int j = 0; j < KK; ++j) {                                              \
        row0[j] = rp0[i * SW2 + j];                                               \
        row1[j] = rp1[i * SW2 + j];                                               \
      }                                                                           \
      _Pragma("unroll")                                                           \
      for (int j = 0; j < KK; ++j) {                                              \
        if (i < 7) {                                                              \
          const float a0 = __builtin_amdgcn_exp2f(                                \
              fmaf(qv00, row0[j].x, qe00[(HALFC) ? j : i]));                      \
          const float a1 = __builtin_amdgcn_exp2f(                                \
              fmaf(qv10, row1[j].x, qe10[(HALFC) ? j : i]));                      \
          s00 += a0; o00 = fmaf(a0, row0[j].y, o00);                              \
          s10 += a1; o10 = fmaf(a1, row1[j].y, o10);                              \
        }                                                                         \
        if (i >= 1) {                                                             \
          const float a0 = __builtin_amdgcn_exp2f(                                \
              fmaf(qv01, row0[j].x, qe01[(HALFC) ? j : (i - 1)]));                \
          const float a1 = __builtin_amdgcn_exp2f(                                \
              fmaf(qv11, row1[j].x, qe11[(HALFC) ? j : (i - 1)]));                \
          s01 += a0; o01 = fmaf(a0, row0[j].y, o01);                              \
          s11 += a1; o11 = fmaf(a1, row1[j].y, o11);                              \
        }                                                                         \
      }                                                                           \
    }                                                                             \
    ob[0]          = o00 * __builtin_amdgcn_rcpf(s00);                            \
    ob[Wc]         = o01 * __builtin_amdgcn_rcpf(s01);                            \
    ob[PLANE]      = o10 * __builtin_amdgcn_rcpf(s10);                            \
    ob[PLANE + Wc] = o11 * __builtin_amdgcn_rcpf(s11);                            \
  }

__global__ __launch_bounds__(256)
void sasa_kernel(const float* __restrict__ x,
                 const float* __restrict__ wq,
                 const float* __restrict__ wk,
                 const float* __restrict__ wv,
                 const float* __restrict__ h_emb,
                 const float* __restrict__ w_emb,
                 float* __restrict__ out)
{
    __shared__ float2 kvs[OCB][SH][SW2];   // 15200 B

    const int tid = threadIdx.x;
    // XCD-aware bijective swizzle: each XCD owns 288 consecutive logical blocks.
    const int L = (blockIdx.x & 7) * (NB / 8) + (blockIdx.x >> 3);
    const int tile    = L % TILES;
    const int rest    = L / TILES;
    const int quarter = rest & 3;      // oc_global = quarter*2 + {0,1}
    const int gi      = (rest >> 2) & 7;
    const int b       = rest >> 5;
    const int half    = quarter >> 1;  // 0 -> h_emb, 1 -> w_emb
    const int th0     = (tile / TILES_W) * TH;
    const int tw0     = (tile % TILES_W) * TW;

    const float* xb  = x  + (size_t)(b * Cc + gi * IG) * PLANE;
    const float* wqg = wq + gi * OG * IG + quarter * OCB * IG;  // block-uniform
    const float* wkg = wk + gi * OG * IG + quarter * OCB * IG;
    const float* wvg = wv + gi * OG * IG + quarter * OCB * IG;
    const float* eb  = (half ? w_emb : h_emb) + gi * (OG / 2) * KK
                                              + (quarter & 1) * OCB * KK;

    // ---- q-pixel loads issued first so HBM latency hides under phase 1 ----
    const int tx = tid & 15;
    const int r0 = 2 * (tid >> 4);     // local rows r0, r0+1
    const int h0 = th0 + r0;
    const int wg = tw0 + tx;
    float xc0[IG], xc1[IG];
    {
        const float* xp = xb + (size_t)h0 * Wc + wg;
        #pragma unroll
        for (int i = 0; i < IG; ++i) {
            xc0[i] = xp[i * PLANE];
            xc1[i] = xp[i * PLANE + Wc];
        }
    }

    // ---- Phase 1: k,v (grouped 1x1 conv) over 38x22 halo -> LDS float2 ----
    for (int e = tid; e < SH * SWD; e += 256) {
        const int hy = e / SWD, hx = e - hy * SWD;
        const int gy = th0 + hy - PAD;
        const int gx = tw0 + hx - PAD;
        const bool valid = ((unsigned)gy < (unsigned)Hc) && ((unsigned)gx < (unsigned)Wc);
        float xv[IG];
        #pragma unroll
        for (int i = 0; i < IG; ++i)
            xv[i] = valid ? xb[i * PLANE + gy * Wc + gx] : 0.0f;
        #pragma unroll
        for (int oc = 0; oc < OCB; ++oc) {
            float ka = 0.f, va = 0.f;
            #pragma unroll
            for (int i = 0; i < IG; ++i) {
                ka = fmaf(xv[i], wkg[oc * IG + i], ka);
                va = fmaf(xv[i], wvg[oc * IG + i], va);
            }
            kvs[oc][hy][hx] = make_float2(ka, va);
        }
    }

    // q projections + qe = qv*e precompute before the barrier; xc regs retire.
    float qv00, qv01, qv10, qv11;      // qv[oc][px]
    {
        float a0 = 0.f, a1 = 0.f, b0 = 0.f, b1 = 0.f;
        #pragma unroll
        for (int i = 0; i < IG; ++i) {
            const float w0 = wqg[i], w1 = wqg[IG + i];
            a0 = fmaf(xc0[i], w0, a0);
            a1 = fmaf(xc1[i], w0, a1);
            b0 = fmaf(xc0[i], w1, b0);
            b1 = fmaf(xc1[i], w1, b1);
        }
        qv00 = a0 * LOG2E; qv01 = a1 * LOG2E;
        qv10 = b0 * LOG2E; qv11 = b1 * LOG2E;
    }
    float qe00[KK], qe01[KK], qe10[KK], qe11[KK];
    #pragma unroll
    for (int t = 0; t < KK; ++t) {
        const float e0 = eb[t], e1 = eb[KK + t];
        qe00[t] = qv00 * e0; qe01[t] = qv01 * e0;
        qe10[t] = qv10 * e1; qe11[t] = qv11 * e1;
    }
    __syncthreads();

    // ---- Phase 2: attention; thread owns pixels (r0, tx) and (r0+1, tx) ----
    float* ob = out + (size_t)(b * Cc + gi * OG + quarter * OCB) * PLANE
                    + (size_t)h0 * Wc + wg;

    if (half == 0) { PHASE2(0) } else { PHASE2(1) }
}

extern "C" void kernel_launch(void* const* d_in, const int* in_sizes, int n_in,
                              void* d_out, int out_size, void* d_ws, size_t ws_size,
                              hipStream_t stream)
{
    const float* x     = (const float*)d_in[0];
    const float* wq    = (const float*)d_in[1];
    const float* wk    = (const float*)d_in[2];
    const float* wv    = (const float*)d_in[3];
    const float* h_emb = (const float*)d_in[4];
    const float* w_emb = (const float*)d_in[5];
    float* out = (float*)d_out;

    sasa_kernel<<<NB, 256, 0, stream>>>(x, wq, wk, wv, h_emb, w_emb, out);
}